// Round 1
// baseline (179.659 us; speedup 1.0000x reference)
//
#include <hip/hip_runtime.h>

typedef __bf16 bf16x8 __attribute__((ext_vector_type(8)));
typedef float f32x4 __attribute__((ext_vector_type(4)));

#define T_LEN 4096
#define HS_D 64

// ---------------- W fp32 -> bf16 (ws) ----------------
__global__ __launch_bounds__(256) void convert_w_kernel(
    const float* __restrict__ Wq, const float* __restrict__ Wk,
    const float* __restrict__ Wv, __bf16* __restrict__ wb)
{
    int i = blockIdx.x * 256 + threadIdx.x;  // exactly 196608 threads
    if (i < 65536)       wb[i] = (__bf16)Wq[i];
    else if (i < 131072) wb[i] = (__bf16)Wk[i - 65536];
    else                 wb[i] = (__bf16)Wv[i - 131072];
}

// ---------------- QKV projection: M=16384, N=192, K=1024 ----------------
// out: qb [16384][64] bf16, kb [16384][64] bf16, vt [4][64][4096] bf16 (V^T)
__global__ __launch_bounds__(256) void proj_kernel(
    const float* __restrict__ x, const __bf16* __restrict__ wb,
    __bf16* __restrict__ qb, __bf16* __restrict__ kb, __bf16* __restrict__ vt)
{
    __shared__ __bf16 xs[64][32];
    __shared__ __bf16 wl[192][32];
    const int tid  = threadIdx.x;
    const int wave = tid >> 6, lane = tid & 63;
    const int l15 = lane & 15, l4 = lane >> 4;
    const size_t m0 = (size_t)blockIdx.x * 64;

    f32x4 acc[4][3];
    #pragma unroll
    for (int a = 0; a < 4; a++)
        #pragma unroll
        for (int bn = 0; bn < 3; bn++) acc[a][bn] = (f32x4){0.f, 0.f, 0.f, 0.f};

    const int xrow = tid >> 2, xpart = tid & 3;

    for (int k0 = 0; k0 < 1024; k0 += 32) {
        // stage x tile (64x32), fp32 -> bf16
        const float* src = x + (m0 + xrow) * 1024 + k0 + xpart * 8;
        float4 f0 = *(const float4*)(src);
        float4 f1 = *(const float4*)(src + 4);
        __bf16* dx = &xs[xrow][xpart * 8];
        dx[0] = (__bf16)f0.x; dx[1] = (__bf16)f0.y; dx[2] = (__bf16)f0.z; dx[3] = (__bf16)f0.w;
        dx[4] = (__bf16)f1.x; dx[5] = (__bf16)f1.y; dx[6] = (__bf16)f1.z; dx[7] = (__bf16)f1.w;
        // stage W tile (192x32) bf16
        #pragma unroll
        for (int j = 0; j < 3; j++) {
            int c = tid + 256 * j;
            int row = c >> 2, part = c & 3;
            *(bf16x8*)(&wl[row][part * 8]) = *(const bf16x8*)(wb + row * 1024 + k0 + part * 8);
        }
        __syncthreads();
        bf16x8 af[4], bfr[3];
        #pragma unroll
        for (int mf = 0; mf < 4; mf++) af[mf] = *(const bf16x8*)(&xs[mf * 16 + l15][l4 * 8]);
        #pragma unroll
        for (int nf = 0; nf < 3; nf++) bfr[nf] = *(const bf16x8*)(&wl[wave * 48 + nf * 16 + l15][l4 * 8]);
        #pragma unroll
        for (int mf = 0; mf < 4; mf++)
            #pragma unroll
            for (int nf = 0; nf < 3; nf++)
                acc[mf][nf] = __builtin_amdgcn_mfma_f32_16x16x32_bf16(af[mf], bfr[nf], acc[mf][nf], 0, 0, 0);
        __syncthreads();
    }

    // epilogue: C layout col = l15, row = l4*4 + r
    #pragma unroll
    for (int mf = 0; mf < 4; mf++) {
        #pragma unroll
        for (int nf = 0; nf < 3; nf++) {
            int n = wave * 48 + nf * 16 + l15;
            #pragma unroll
            for (int r = 0; r < 4; r++) {
                size_t mrow = m0 + mf * 16 + l4 * 4 + r;
                __bf16 bv = (__bf16)acc[mf][nf][r];
                if (n < 64)       qb[mrow * 64 + n] = bv;
                else if (n < 128) kb[mrow * 64 + (n - 64)] = bv;
                else {
                    int bb = (int)(mrow >> 12), tt = (int)(mrow & 4095);
                    vt[((size_t)bb * 64 + (n - 128)) * 4096 + tt] = bv;
                }
            }
        }
    }
}

// ---------------- RoPE in-place on q,k (interleaved pairs) ----------------
__global__ __launch_bounds__(256) void rope_kernel(__bf16* qb, __bf16* kb)
{
    int idx = blockIdx.x * 256 + threadIdx.x;  // exactly 4*4096*32 threads
    int i = idx & 31;
    int t = (idx >> 5) & 4095;
    size_t base = (size_t)(idx >> 5) * 64 + 2 * i;
    // inv_freq = 10000^(-2i/64) = 2^(-i * log2(10000)/32)
    float inv = __builtin_exp2f((float)i * (-13.287712379549449f / 32.f));
    float ang = (float)t * inv;
    float sn, cs;
    sincosf(ang, &sn, &cs);
    float qe = (float)qb[base], qo = (float)qb[base + 1];
    qb[base]     = (__bf16)(qe * cs - qo * sn);
    qb[base + 1] = (__bf16)(qe * sn + qo * cs);
    float ke = (float)kb[base], ko = (float)kb[base + 1];
    kb[base]     = (__bf16)(ke * cs - ko * sn);
    kb[base + 1] = (__bf16)(ke * sn + ko * cs);
}

// ---------------- causal flash attention ----------------
// grid 256 = 4 batches * 64 q-tiles of 64 rows; 4 waves, wave owns 16 q-rows
__global__ __launch_bounds__(256) void flash_kernel(
    const __bf16* __restrict__ qb, const __bf16* __restrict__ kb,
    const __bf16* __restrict__ vt, float* __restrict__ out)
{
    __shared__ __bf16 plds[4][16][32];
    const int blk = blockIdx.x;
    const int b = blk >> 6;
    const int q0 = (blk & 63) * 64;
    const int tid = threadIdx.x;
    const int wave = tid >> 6, lane = tid & 63;
    const int l15 = lane & 15, l4 = lane >> 4;
    const int qrow0 = q0 + wave * 16;

    // Q A-frags held in registers for the whole k-loop
    const __bf16* qpb = qb + ((size_t)b * T_LEN + qrow0) * 64;
    bf16x8 qa0 = *(const bf16x8*)(qpb + (size_t)l15 * 64 + l4 * 8);
    bf16x8 qa1 = *(const bf16x8*)(qpb + (size_t)l15 * 64 + 32 + l4 * 8);

    float mrow[4], lsum[4];
    f32x4 oacc[4];
    #pragma unroll
    for (int r = 0; r < 4; r++) { mrow[r] = -1e30f; lsum[r] = 0.f; }
    #pragma unroll
    for (int n = 0; n < 4; n++) oacc[n] = (f32x4){0.f, 0.f, 0.f, 0.f};

    const __bf16* kbb = kb + (size_t)b * T_LEN * 64;
    const __bf16* vtb = vt + (size_t)b * 64 * T_LEN;
    const int ntiles = (qrow0 + 15) / 32 + 1;  // causal bound for this wave

    for (int kt = 0; kt < ntiles; kt++) {
        const int kc0 = kt * 32;
        // S = Q K^T  (16 rows x 32 cols)
        f32x4 s[2];
        #pragma unroll
        for (int n = 0; n < 2; n++) {
            const __bf16* kr = kbb + (size_t)(kc0 + n * 16 + l15) * 64 + l4 * 8;
            bf16x8 k0 = *(const bf16x8*)(kr);
            bf16x8 k1 = *(const bf16x8*)(kr + 32);
            f32x4 a = (f32x4){0.f, 0.f, 0.f, 0.f};
            a = __builtin_amdgcn_mfma_f32_16x16x32_bf16(qa0, k0, a, 0, 0, 0);
            a = __builtin_amdgcn_mfma_f32_16x16x32_bf16(qa1, k1, a, 0, 0, 0);
            s[n] = a;
        }
        // scale + causal mask
        float pv[2][4], tmax[4];
        #pragma unroll
        for (int r = 0; r < 4; r++) tmax[r] = -1e30f;
        #pragma unroll
        for (int n = 0; n < 2; n++) {
            int col = kc0 + n * 16 + l15;
            #pragma unroll
            for (int r = 0; r < 4; r++) {
                int row = qrow0 + l4 * 4 + r;
                float v = s[n][r] * 0.125f;
                v = (col <= row) ? v : -1e30f;
                pv[n][r] = v;
                tmax[r] = fmaxf(tmax[r], v);
            }
        }
        // row max across the 16 lanes holding this row
        #pragma unroll
        for (int off = 1; off < 16; off <<= 1)
            #pragma unroll
            for (int r = 0; r < 4; r++)
                tmax[r] = fmaxf(tmax[r], __shfl_xor(tmax[r], off, 16));
        float alpha[4];
        #pragma unroll
        for (int r = 0; r < 4; r++) {
            float mn = fmaxf(mrow[r], tmax[r]);
            alpha[r] = __expf(mrow[r] - mn);
            mrow[r] = mn;
        }
        float tsum[4] = {0.f, 0.f, 0.f, 0.f};
        #pragma unroll
        for (int n = 0; n < 2; n++)
            #pragma unroll
            for (int r = 0; r < 4; r++) {
                float p = __expf(pv[n][r] - mrow[r]);
                pv[n][r] = p;
                tsum[r] += p;
            }
        #pragma unroll
        for (int off = 1; off < 16; off <<= 1)
            #pragma unroll
            for (int r = 0; r < 4; r++)
                tsum[r] += __shfl_xor(tsum[r], off, 16);
        #pragma unroll
        for (int r = 0; r < 4; r++) lsum[r] = lsum[r] * alpha[r] + tsum[r];
        #pragma unroll
        for (int n = 0; n < 4; n++)
            #pragma unroll
            for (int r = 0; r < 4; r++)
                oacc[n][r] *= alpha[r];
        // P (C-layout) -> LDS -> A-frag layout; within-wave, no barrier needed,
        // but fence the compiler so it can't reorder the read above the writes.
        #pragma unroll
        for (int n = 0; n < 2; n++)
            #pragma unroll
            for (int r = 0; r < 4; r++)
                plds[wave][l4 * 4 + r][n * 16 + l15] = (__bf16)pv[n][r];
        asm volatile("" ::: "memory");
        bf16x8 pa = *(const bf16x8*)(&plds[wave][l15][l4 * 8]);
        // O += P V   (V^T rows are contiguous in t)
        #pragma unroll
        for (int n = 0; n < 4; n++) {
            bf16x8 vf = *(const bf16x8*)(vtb + (size_t)(n * 16 + l15) * T_LEN + kc0 + l4 * 8);
            oacc[n] = __builtin_amdgcn_mfma_f32_16x16x32_bf16(pa, vf, oacc[n], 0, 0, 0);
        }
    }

    float* ob = out + ((size_t)b * T_LEN + qrow0) * 64;
    float invl[4];
    #pragma unroll
    for (int r = 0; r < 4; r++) invl[r] = 1.f / lsum[r];
    #pragma unroll
    for (int n = 0; n < 4; n++)
        #pragma unroll
        for (int r = 0; r < 4; r++)
            ob[(size_t)(l4 * 4 + r) * 64 + n * 16 + l15] = oacc[n][r] * invl[r];
}

extern "C" void kernel_launch(void* const* d_in, const int* in_sizes, int n_in,
                              void* d_out, int out_size, void* d_ws, size_t ws_size,
                              hipStream_t stream)
{
    const float* x  = (const float*)d_in[0];
    const float* Wq = (const float*)d_in[1];
    const float* Wk = (const float*)d_in[2];
    const float* Wv = (const float*)d_in[3];
    float* out = (float*)d_out;

    __bf16* qb = (__bf16*)d_ws;          // 4*4096*64 bf16 = 2 MB
    __bf16* kb = qb + 1048576;           // 2 MB
    __bf16* vt = kb + 1048576;           // 2 MB (V transposed [b][d][t])
    __bf16* wb = vt + 1048576;           // 192*1024 bf16 = 384 KB

    convert_w_kernel<<<768, 256, 0, stream>>>(Wq, Wk, Wv, wb);
    proj_kernel<<<256, 256, 0, stream>>>(x, wb, qb, kb, vt);
    rope_kernel<<<2048, 256, 0, stream>>>(qb, kb);
    flash_kernel<<<256, 256, 0, stream>>>(qb, kb, vt, out);
}

// Round 2
// 144.592 us; speedup vs baseline: 1.2425x; 1.2425x over previous
//
#include <hip/hip_runtime.h>

typedef __bf16 bf16x8 __attribute__((ext_vector_type(8)));
typedef __bf16 bf16x4 __attribute__((ext_vector_type(4)));
typedef float f32x4 __attribute__((ext_vector_type(4)));

#define T_LEN 4096

__device__ __forceinline__ f32x4 mfma16(bf16x8 a, bf16x8 b, f32x4 c) {
    return __builtin_amdgcn_mfma_f32_16x16x32_bf16(a, b, c, 0, 0, 0);
}

// ---------------- W fp32 -> bf16 (ws), vectorized ----------------
__global__ __launch_bounds__(256) void convert_w_kernel(
    const float* __restrict__ Wq, const float* __restrict__ Wk,
    const float* __restrict__ Wv, __bf16* __restrict__ wb)
{
    int i = blockIdx.x * 256 + threadIdx.x;      // 49152 threads, 4 elems each
    int m = i >> 14, off = (i & 16383) << 2;
    const float* s = (m == 0 ? Wq : (m == 1 ? Wk : Wv)) + off;
    float4 f = *(const float4*)s;
    bf16x4 h = { (__bf16)f.x, (__bf16)f.y, (__bf16)f.z, (__bf16)f.w };
    *(bf16x4*)(wb + (m << 16) + off) = h;
}

// ---------------- QKV projection (M=16384,N=192,K=1024) + fused RoPE ------
// 512 blocks x 32 rows. out: qb/kb [16384][64] bf16 (rope applied), vt [4][64][4096]
__global__ __launch_bounds__(256) void proj_kernel(
    const float* __restrict__ x, const __bf16* __restrict__ wb,
    __bf16* __restrict__ qb, __bf16* __restrict__ kb, __bf16* __restrict__ vt)
{
    __shared__ __bf16 xs[32][72];     // pad 72: conflict-free b128, 16B-aligned rows
    __shared__ __bf16 wl[192][72];
    const int tid  = threadIdx.x;
    const int wave = tid >> 6, lane = tid & 63;
    const int l15 = lane & 15, l4 = lane >> 4;
    const size_t m0 = (size_t)blockIdx.x * 32;

    f32x4 acc[2][3];
    #pragma unroll
    for (int a = 0; a < 2; a++)
        #pragma unroll
        for (int bn = 0; bn < 3; bn++) acc[a][bn] = (f32x4){0.f, 0.f, 0.f, 0.f};

    const int xrow = tid >> 3, xcp = (tid & 7) * 8;

    for (int k0 = 0; k0 < 1024; k0 += 64) {
        const float* src = x + (m0 + xrow) * 1024 + k0 + xcp;
        float4 f0 = *(const float4*)src;
        float4 f1 = *(const float4*)(src + 4);
        bf16x8 h = {(__bf16)f0.x, (__bf16)f0.y, (__bf16)f0.z, (__bf16)f0.w,
                    (__bf16)f1.x, (__bf16)f1.y, (__bf16)f1.z, (__bf16)f1.w};
        *(bf16x8*)&xs[xrow][xcp] = h;
        #pragma unroll
        for (int j = 0; j < 6; j++) {
            int c = tid + 256 * j;
            int wrow = c >> 3, wpart = (c & 7) * 8;
            *(bf16x8*)&wl[wrow][wpart] = *(const bf16x8*)(wb + wrow * 1024 + k0 + wpart);
        }
        __syncthreads();
        bf16x8 af[2][2], bfr[3][2];
        #pragma unroll
        for (int mf = 0; mf < 2; mf++)
            #pragma unroll
            for (int c = 0; c < 2; c++)
                af[mf][c] = *(const bf16x8*)&xs[mf * 16 + l15][c * 32 + l4 * 8];
        #pragma unroll
        for (int nf = 0; nf < 3; nf++)
            #pragma unroll
            for (int c = 0; c < 2; c++)
                bfr[nf][c] = *(const bf16x8*)&wl[wave * 48 + nf * 16 + l15][c * 32 + l4 * 8];
        #pragma unroll
        for (int mf = 0; mf < 2; mf++)
            #pragma unroll
            for (int nf = 0; nf < 3; nf++)
                #pragma unroll
                for (int c = 0; c < 2; c++)
                    acc[mf][nf] = mfma16(af[mf][c], bfr[nf][c], acc[mf][nf]);
        __syncthreads();
    }

    // epilogue: C layout col = l15 (n), row = l4*4 + r (m); rope fused for q,k
    #pragma unroll
    for (int mf = 0; mf < 2; mf++) {
        #pragma unroll
        for (int nf = 0; nf < 3; nf++) {
            int n = wave * 48 + nf * 16 + l15;
            #pragma unroll
            for (int r = 0; r < 4; r++) {
                size_t mrow = m0 + mf * 16 + l4 * 4 + r;
                float val = acc[mf][nf][r];
                float partner = __shfl_xor(val, 1);   // pair (even,odd) exchange
                if (n < 128) {
                    int i = (n & 63) >> 1;
                    int t = (int)(mrow & 4095);
                    float inv = __builtin_exp2f((float)i * (-13.287712379549449f / 32.f));
                    float ang = (float)t * inv;
                    float sn, cs;
                    sincosf(ang, &sn, &cs);
                    float res = (n & 1) ? (partner * sn + val * cs)
                                        : (val * cs - partner * sn);
                    __bf16 bv = (__bf16)res;
                    if (n < 64) qb[mrow * 64 + n] = bv;
                    else        kb[mrow * 64 + (n - 64)] = bv;
                } else {
                    int bb = (int)(mrow >> 12), tt = (int)(mrow & 4095);
                    vt[((size_t)bb * 64 + (n - 128)) * 4096 + tt] = (__bf16)val;
                }
            }
        }
    }
}

// ---------------- causal flash attention, in-block split-K x4 ----------------
// 512 blocks (heavy-first), 8 waves: rg = wave&1 (16 q-rows), sp = wave>>1 (k mod 4)
// Swapped orientation: S^T = mfma(K, Q): C col=l15=q, row=l4*4+r=k -> row stats lane-local
__global__ __launch_bounds__(512) void flash_kernel(
    const __bf16* __restrict__ qb, const __bf16* __restrict__ kb,
    const __bf16* __restrict__ vt, float* __restrict__ out)
{
    __shared__ float ods[8][64][17];
    __shared__ float mls[8][2][64];
    __shared__ __bf16 pt[8][16][72];

    const int tid = threadIdx.x;
    const int wave = tid >> 6, lane = tid & 63;
    const int l15 = lane & 15, l4 = lane >> 4;
    const int b = blockIdx.x & 3;
    const int qq = 127 - (blockIdx.x >> 2);   // heavy q-tiles dispatched first
    const int q0 = qq * 32;
    const int rg = wave & 1, sp = wave >> 1;
    const int qrow0 = q0 + rg * 16;

    const __bf16* qpb = qb + ((size_t)b * T_LEN + qrow0) * 64;
    bf16x8 qa0 = *(const bf16x8*)(qpb + l15 * 64 + l4 * 8);
    bf16x8 qa1 = *(const bf16x8*)(qpb + l15 * 64 + 32 + l4 * 8);

    const __bf16* kbb = kb + (size_t)b * T_LEN * 64;
    const __bf16* vtb = vt + (size_t)b * 64 * T_LEN;

    float m = -1e30f, l = 0.f;
    f32x4 oacc[4];
    #pragma unroll
    for (int n = 0; n < 4; n++) oacc[n] = (f32x4){0.f, 0.f, 0.f, 0.f};

    // kc0 and qrow0 are both multiples of 16, so every processed tile has
    // kc0 <= qrow0 -> each lane's row has >=1 unmasked col -> tmax finite.
    const int ntiles = ((qrow0 + 15) >> 6) + 1;
    for (int kt = sp; kt < ntiles; kt += 4) {
        const int kc0 = kt << 6;
        const __bf16* kr = kbb + (size_t)(kc0 + l15) * 64 + l4 * 8;
        f32x4 s[4];
        #pragma unroll
        for (int mf = 0; mf < 4; mf++) {
            bf16x8 k0 = *(const bf16x8*)(kr + mf * 1024);
            bf16x8 k1 = *(const bf16x8*)(kr + mf * 1024 + 32);
            f32x4 a = (f32x4){0.f, 0.f, 0.f, 0.f};
            a = mfma16(k0, qa0, a);
            a = mfma16(k1, qa1, a);
            s[mf] = a;
        }
        float p[4][4];
        float tmax = -1e30f;
        const bool needmask = (kc0 + 63 > qrow0);
        #pragma unroll
        for (int mf = 0; mf < 4; mf++) {
            int kbase = kc0 + mf * 16 + l4 * 4;
            #pragma unroll
            for (int r = 0; r < 4; r++) {
                float v = s[mf][r] * 0.180336884f;   // (1/8) * log2(e)
                if (needmask && (kbase + r > qrow0 + l15)) v = -1e30f;
                p[mf][r] = v;
                tmax = fmaxf(tmax, v);
            }
        }
        tmax = fmaxf(tmax, __shfl_xor(tmax, 16));
        tmax = fmaxf(tmax, __shfl_xor(tmax, 32));
        const float mnew = fmaxf(m, tmax);
        const float alpha = __builtin_exp2f(m - mnew);
        m = mnew;
        float tsum = 0.f;
        #pragma unroll
        for (int mf = 0; mf < 4; mf++)
            #pragma unroll
            for (int r = 0; r < 4; r++) {
                float e = __builtin_exp2f(p[mf][r] - mnew);
                p[mf][r] = e;
                tsum += e;
            }
        tsum += __shfl_xor(tsum, 16);
        tsum += __shfl_xor(tsum, 32);
        l = l * alpha + tsum;
        #pragma unroll
        for (int n = 0; n < 4; n++) {
            oacc[n][0] *= alpha; oacc[n][1] *= alpha;
            oacc[n][2] *= alpha; oacc[n][3] *= alpha;
        }
        // P^T -> LDS [q][k] (b64 writes), read back as b128 B-frags
        #pragma unroll
        for (int mf = 0; mf < 4; mf++) {
            bf16x4 pk = {(__bf16)p[mf][0], (__bf16)p[mf][1],
                         (__bf16)p[mf][2], (__bf16)p[mf][3]};
            *(bf16x4*)&pt[wave][l15][mf * 16 + l4 * 4] = pk;
        }
        asm volatile("" ::: "memory");
        bf16x8 pb0 = *(const bf16x8*)&pt[wave][l15][l4 * 8];
        bf16x8 pb1 = *(const bf16x8*)&pt[wave][l15][32 + l4 * 8];
        #pragma unroll
        for (int nf = 0; nf < 4; nf++) {
            const __bf16* vr = vtb + (size_t)(nf * 16 + l15) * T_LEN + kc0 + l4 * 8;
            bf16x8 v0 = *(const bf16x8*)(vr);
            bf16x8 v1 = *(const bf16x8*)(vr + 32);
            oacc[nf] = mfma16(v0, pb0, oacc[nf]);
            oacc[nf] = mfma16(v1, pb1, oacc[nf]);
        }
    }

    // publish partials: O^T frags (col=l15=q, row=l4*4+r=d) + per-lane m,l
    #pragma unroll
    for (int nf = 0; nf < 4; nf++)
        #pragma unroll
        for (int r = 0; r < 4; r++)
            ods[wave][lane][nf * 4 + r] = oacc[nf][r];
    mls[wave][0][lane] = m;
    mls[wave][1][lane] = l;
    __syncthreads();

    if (wave < 2) {   // wave w merges partials of row-group w: waves {w, w+2, w+4, w+6}
        float mm[4], llv[4];
        float M = -1e30f;
        #pragma unroll
        for (int p2 = 0; p2 < 4; p2++) {
            mm[p2]  = mls[wave + 2 * p2][0][lane];
            llv[p2] = mls[wave + 2 * p2][1][lane];
            M = fmaxf(M, mm[p2]);
        }
        float w[4], L = 0.f;
        #pragma unroll
        for (int p2 = 0; p2 < 4; p2++) {
            w[p2] = __builtin_exp2f(mm[p2] - M);
            L += w[p2] * llv[p2];
        }
        const float invL = 1.f / L;
        const int qrow = q0 + wave * 16 + l15;
        float* ob = out + ((size_t)b * T_LEN + qrow) * 64;
        #pragma unroll
        for (int j = 0; j < 16; j++) {
            float o = 0.f;
            #pragma unroll
            for (int p2 = 0; p2 < 4; p2++) o += w[p2] * ods[wave + 2 * p2][lane][j];
            int d = (j >> 2) * 16 + l4 * 4 + (j & 3);
            ob[d] = o * invL;
        }
    }
}

extern "C" void kernel_launch(void* const* d_in, const int* in_sizes, int n_in,
                              void* d_out, int out_size, void* d_ws, size_t ws_size,
                              hipStream_t stream)
{
    const float* x  = (const float*)d_in[0];
    const float* Wq = (const float*)d_in[1];
    const float* Wk = (const float*)d_in[2];
    const float* Wv = (const float*)d_in[3];
    float* out = (float*)d_out;

    __bf16* qb = (__bf16*)d_ws;          // 2 MB (rope applied)
    __bf16* kb = qb + 1048576;           // 2 MB (rope applied)
    __bf16* vt = kb + 1048576;           // 2 MB (V transposed [b][d][t])
    __bf16* wb = vt + 1048576;           // 384 KB

    convert_w_kernel<<<192, 256, 0, stream>>>(Wq, Wk, Wv, wb);
    proj_kernel<<<512, 256, 0, stream>>>(x, wb, qb, kb, vt);
    flash_kernel<<<512, 512, 0, stream>>>(qb, kb, vt, out);
}

// Round 4
// 92.537 us; speedup vs baseline: 1.9415x; 1.5625x over previous
//
#include <hip/hip_runtime.h>

typedef __bf16 bf16x8 __attribute__((ext_vector_type(8)));
typedef __bf16 bf16x4 __attribute__((ext_vector_type(4)));
typedef float f32x4 __attribute__((ext_vector_type(4)));
typedef float f32x16 __attribute__((ext_vector_type(16)));
typedef unsigned int u32;

#define T_LEN 4096

__device__ __forceinline__ f32x4 mfma16(bf16x8 a, bf16x8 b, f32x4 c) {
    return __builtin_amdgcn_mfma_f32_16x16x32_bf16(a, b, c, 0, 0, 0);
}
__device__ __forceinline__ f32x16 mfma32(bf16x8 a, bf16x8 b, f32x16 c) {
    return __builtin_amdgcn_mfma_f32_32x32x16_bf16(a, b, c, 0, 0, 0);
}
__device__ __forceinline__ u32 packbf(float lo, float hi) {
    union { __bf16 e[2]; u32 w; } u;
    u.e[0] = (__bf16)lo; u.e[1] = (__bf16)hi;
    return u.w;
}
__device__ __forceinline__ f32x16 zero16() {
    f32x16 z;
    #pragma unroll
    for (int i = 0; i < 16; i++) z[i] = 0.f;
    return z;
}

// ---------------- W fp32 -> bf16 (ws), vectorized ----------------
__global__ __launch_bounds__(256) void convert_w_kernel(
    const float* __restrict__ Wq, const float* __restrict__ Wk,
    const float* __restrict__ Wv, __bf16* __restrict__ wb)
{
    int i = blockIdx.x * 256 + threadIdx.x;      // 49152 threads, 4 elems each
    int m = i >> 14, off = (i & 16383) << 2;
    const float* s = (m == 0 ? Wq : (m == 1 ? Wk : Wv)) + off;
    float4 f = *(const float4*)s;
    bf16x4 h = { (__bf16)f.x, (__bf16)f.y, (__bf16)f.z, (__bf16)f.w };
    *(bf16x4*)(wb + (m << 16) + off) = h;
}

// ---------------- QKV projection (M=16384,N=192,K=1024) + fused RoPE ------
__global__ __launch_bounds__(256) void proj_kernel(
    const float* __restrict__ x, const __bf16* __restrict__ wb,
    __bf16* __restrict__ qb, __bf16* __restrict__ kb, __bf16* __restrict__ vt)
{
    __shared__ __bf16 xs[32][72];
    __shared__ __bf16 wl[192][72];
    const int tid  = threadIdx.x;
    const int wave = tid >> 6, lane = tid & 63;
    const int l15 = lane & 15, l4 = lane >> 4;
    const size_t m0 = (size_t)blockIdx.x * 32;

    f32x4 acc[2][3];
    #pragma unroll
    for (int a = 0; a < 2; a++)
        #pragma unroll
        for (int bn = 0; bn < 3; bn++) acc[a][bn] = (f32x4){0.f, 0.f, 0.f, 0.f};

    const int xrow = tid >> 3, xcp = (tid & 7) * 8;

    for (int k0 = 0; k0 < 1024; k0 += 64) {
        const float* src = x + (m0 + xrow) * 1024 + k0 + xcp;
        float4 f0 = *(const float4*)src;
        float4 f1 = *(const float4*)(src + 4);
        bf16x8 h = {(__bf16)f0.x, (__bf16)f0.y, (__bf16)f0.z, (__bf16)f0.w,
                    (__bf16)f1.x, (__bf16)f1.y, (__bf16)f1.z, (__bf16)f1.w};
        *(bf16x8*)&xs[xrow][xcp] = h;
        #pragma unroll
        for (int j = 0; j < 6; j++) {
            int c = tid + 256 * j;
            int wrow = c >> 3, wpart = (c & 7) * 8;
            *(bf16x8*)&wl[wrow][wpart] = *(const bf16x8*)(wb + wrow * 1024 + k0 + wpart);
        }
        __syncthreads();
        bf16x8 af[2][2], bfr[3][2];
        #pragma unroll
        for (int mf = 0; mf < 2; mf++)
            #pragma unroll
            for (int c = 0; c < 2; c++)
                af[mf][c] = *(const bf16x8*)&xs[mf * 16 + l15][c * 32 + l4 * 8];
        #pragma unroll
        for (int nf = 0; nf < 3; nf++)
            #pragma unroll
            for (int c = 0; c < 2; c++)
                bfr[nf][c] = *(const bf16x8*)&wl[wave * 48 + nf * 16 + l15][c * 32 + l4 * 8];
        #pragma unroll
        for (int mf = 0; mf < 2; mf++)
            #pragma unroll
            for (int nf = 0; nf < 3; nf++)
                #pragma unroll
                for (int c = 0; c < 2; c++)
                    acc[mf][nf] = mfma16(af[mf][c], bfr[nf][c], acc[mf][nf]);
        __syncthreads();
    }

    // epilogue: C layout col = l15 (n), row = l4*4 + r (m); rope fused for q,k
    #pragma unroll
    for (int mf = 0; mf < 2; mf++) {
        #pragma unroll
        for (int nf = 0; nf < 3; nf++) {
            int n = wave * 48 + nf * 16 + l15;
            #pragma unroll
            for (int r = 0; r < 4; r++) {
                size_t mrow = m0 + mf * 16 + l4 * 4 + r;
                float val = acc[mf][nf][r];
                float partner = __shfl_xor(val, 1);
                if (n < 128) {
                    int i = (n & 63) >> 1;
                    int t = (int)(mrow & 4095);
                    float inv = __builtin_exp2f((float)i * (-13.287712379549449f / 32.f));
                    float ang = (float)t * inv;
                    float sn, cs;
                    __sincosf(ang, &sn, &cs);
                    float res = (n & 1) ? (partner * sn + val * cs)
                                        : (val * cs - partner * sn);
                    __bf16 bv = (__bf16)res;
                    if (n < 64) qb[mrow * 64 + n] = bv;
                    else        kb[mrow * 64 + (n - 64)] = bv;
                } else {
                    int bb = (int)(mrow >> 12), tt = (int)(mrow & 4095);
                    vt[((size_t)bb * 64 + (n - 128)) * 4096 + tt] = (__bf16)val;
                }
            }
        }
    }
}

// ---------------- causal flash attention, 32x32 MFMA + shfl softmax ----
// 256 blocks = 4 batches x 64 pairs (jA=127-p heavy, jB=p light; 32-row q-blocks)
// 8 waves = 8 k-splits; wave owns all 32 q-rows. Swapped QK^T: lane -> one q col.
__global__ __launch_bounds__(512, 2) void flash_kernel(
    const __bf16* __restrict__ qb, const __bf16* __restrict__ kb,
    const __bf16* __restrict__ vt, float* __restrict__ out)
{
    __shared__ float ods[8][32][68];
    __shared__ float mls[2][8][32];

    const int tid = threadIdx.x;
    const int wave = tid >> 6, lane = tid & 63;
    const int l31 = lane & 31, h = lane >> 5;
    const int b = blockIdx.x & 3;
    const int p = blockIdx.x >> 2;

    const __bf16* kbb = kb + (size_t)b * T_LEN * 64;
    const __bf16* vtb = vt + (size_t)b * 64 * T_LEN;

    #pragma unroll 1
    for (int half = 0; half < 2; half++) {
        const int jt = half ? p : 127 - p;
        const int q0 = jt * 32;
        const int qg = q0 + l31;

        // Q B-frags: col q = l31, k(d) = dc*16 + 8h + j
        const __bf16* qp = qb + ((size_t)b * T_LEN + q0 + l31) * 64 + h * 8;
        bf16x8 qf[4];
        #pragma unroll
        for (int dc = 0; dc < 4; dc++) qf[dc] = *(const bf16x8*)(qp + dc * 16);

        float m = -1e30f, l = 0.f;
        f32x16 o0 = zero16(), o1 = zero16();
        const int nt = (jt >> 1) + 1;

        for (int kt = wave; kt < nt; kt += 8) {
            const int kc0 = kt << 6;
            // K A-frags (row k, col d) + QK^T
            const __bf16* kr0 = kbb + (size_t)(kc0 + l31) * 64 + h * 8;
            const __bf16* kr1 = kr0 + 32 * 64;
            f32x16 s0 = zero16(), s1 = zero16();
            #pragma unroll
            for (int dc = 0; dc < 4; dc++) {
                s0 = mfma32(*(const bf16x8*)(kr0 + dc * 16), qf[dc], s0);
                s1 = mfma32(*(const bf16x8*)(kr1 + dc * 16), qf[dc], s1);
            }
            // V A-frags issued early: rows d = l31(+32), k = cg*16 + 8h + j
            const __bf16* vr0 = vtb + (size_t)l31 * T_LEN + kc0 + h * 8;
            const __bf16* vr1 = vr0 + (size_t)32 * T_LEN;
            bf16x8 vf0[4], vf1[4];
            #pragma unroll
            for (int cg = 0; cg < 4; cg++) {
                vf0[cg] = *(const bf16x8*)(vr0 + cg * 16);
                vf1[cg] = *(const bf16x8*)(vr1 + cg * 16);
            }
            // scale + causal mask; C row k = (r&3) + 8*(r>>2) + 4h (+32 for s1)
            float tmax = -1e30f;
            #pragma unroll
            for (int r = 0; r < 16; r++) {
                float v0 = s0[r] * 0.180336884f;   // (1/8) * log2(e)
                float v1 = s1[r] * 0.180336884f;
                int koff = kc0 + (r & 3) + 8 * (r >> 2) + 4 * h;
                if (koff > qg)      v0 = -1e30f;
                if (koff + 32 > qg) v1 = -1e30f;
                s0[r] = v0; s1[r] = v1;
                tmax = fmaxf(tmax, fmaxf(v0, v1));
            }
            tmax = fmaxf(tmax, __shfl_xor(tmax, 32));
            const float mnew = fmaxf(m, tmax);
            const float alpha = __builtin_exp2f(m - mnew);
            m = mnew;
            float tsum = 0.f;
            #pragma unroll
            for (int r = 0; r < 16; r++) {
                float e0 = __builtin_exp2f(s0[r] - mnew);
                float e1 = __builtin_exp2f(s1[r] - mnew);
                s0[r] = e0; s1[r] = e1;
                tsum += e0 + e1;
            }
            tsum += __shfl_xor(tsum, 32);
            l = l * alpha + tsum;
            #pragma unroll
            for (int r = 0; r < 16; r++) { o0[r] *= alpha; o1[r] *= alpha; }

            // P -> bf16: lane holds k_offs (r&3)+8*(r>>2)+4h; pack pairs to dwords
            u32 d0[8], d1[8];
            #pragma unroll
            for (int i = 0; i < 8; i++) {
                d0[i] = packbf(s0[2 * i], s0[2 * i + 1]);
                d1[i] = packbf(s1[2 * i], s1[2 * i + 1]);
            }
            // Build B-frags (col q=l31, k-within-16 = 8h+j) by exchanging with
            // partner lane (l^32): dw0..3 = {h?r02:d[g], h?r13:d[g+1],
            //                                h?d[g+2]:r02, h?d[g+3]:r13}
            union { u32 w[4]; bf16x8 v; } pf[4];
            #pragma unroll
            for (int cg = 0; cg < 4; cg++) {
                u32* d = (cg < 2) ? d0 : d1;
                const int g = (cg & 1) * 4;
                u32 r02 = __shfl_xor(h ? d[g]     : d[g + 2], 32);
                u32 r13 = __shfl_xor(h ? d[g + 1] : d[g + 3], 32);
                pf[cg].w[0] = h ? r02 : d[g];
                pf[cg].w[1] = h ? r13 : d[g + 1];
                pf[cg].w[2] = h ? d[g + 2] : r02;
                pf[cg].w[3] = h ? d[g + 3] : r13;
            }
            // PV: O^T += V^T P^T
            #pragma unroll
            for (int cg = 0; cg < 4; cg++) {
                o0 = mfma32(vf0[cg], pf[cg].v, o0);
                o1 = mfma32(vf1[cg], pf[cg].v, o1);
            }
        }

        // publish partials: O^T C-layout col q=l31, row d=(r&3)+8*(r>>2)+4h
        #pragma unroll
        for (int c2 = 0; c2 < 4; c2++) {
            f32x4 w0 = {o0[4 * c2], o0[4 * c2 + 1], o0[4 * c2 + 2], o0[4 * c2 + 3]};
            f32x4 w1 = {o1[4 * c2], o1[4 * c2 + 1], o1[4 * c2 + 2], o1[4 * c2 + 3]};
            *(f32x4*)&ods[wave][l31][8 * c2 + 4 * h]      = w0;
            *(f32x4*)&ods[wave][l31][32 + 8 * c2 + 4 * h] = w1;
        }
        if (h == 0) { mls[0][wave][l31] = m; mls[1][wave][l31] = l; }
        __syncthreads();

        // merge 8 splits: thread -> (q = tid>>4, dchunk = tid&15)
        {
            const int q = tid >> 4, dc = tid & 15;
            float M = -1e30f;
            #pragma unroll
            for (int s2 = 0; s2 < 8; s2++) M = fmaxf(M, mls[0][s2][q]);
            float w8[8], L = 0.f;
            #pragma unroll
            for (int s2 = 0; s2 < 8; s2++) {
                float ws = __builtin_exp2f(mls[0][s2][q] - M);
                w8[s2] = ws;
                L += ws * mls[1][s2][q];
            }
            const float invL = 1.f / L;
            f32x4 acc = {0.f, 0.f, 0.f, 0.f};
            #pragma unroll
            for (int s2 = 0; s2 < 8; s2++) {
                f32x4 part = *(const f32x4*)&ods[s2][q][dc * 4];
                acc.x += part.x * w8[s2];
                acc.y += part.y * w8[s2];
                acc.z += part.z * w8[s2];
                acc.w += part.w * w8[s2];
            }
            acc.x *= invL; acc.y *= invL; acc.z *= invL; acc.w *= invL;
            *(f32x4*)(out + ((size_t)b * T_LEN + q0 + q) * 64 + dc * 4) = acc;
        }
        __syncthreads();
    }
}

extern "C" void kernel_launch(void* const* d_in, const int* in_sizes, int n_in,
                              void* d_out, int out_size, void* d_ws, size_t ws_size,
                              hipStream_t stream)
{
    const float* x  = (const float*)d_in[0];
    const float* Wq = (const float*)d_in[1];
    const float* Wk = (const float*)d_in[2];
    const float* Wv = (const float*)d_in[3];
    float* out = (float*)d_out;

    __bf16* qb = (__bf16*)d_ws;          // 2 MB (rope applied)
    __bf16* kb = qb + 1048576;           // 2 MB (rope applied)
    __bf16* vt = kb + 1048576;           // 2 MB (V transposed [b][d][t])
    __bf16* wb = vt + 1048576;           // 384 KB

    convert_w_kernel<<<192, 256, 0, stream>>>(Wq, Wk, Wv, wb);
    proj_kernel<<<512, 256, 0, stream>>>(x, wb, qb, kb, vt);
    flash_kernel<<<256, 512, 0, stream>>>(qb, kb, vt, out);
}

// Round 5
// 66.304 us; speedup vs baseline: 2.7096x; 1.3957x over previous
//
#include <hip/hip_runtime.h>

typedef __bf16 bf16x8 __attribute__((ext_vector_type(8)));
typedef __bf16 bf16x4 __attribute__((ext_vector_type(4)));
typedef float f32x4 __attribute__((ext_vector_type(4)));
typedef float f32x16 __attribute__((ext_vector_type(16)));
typedef unsigned int u32;

#define T_LEN 4096

__device__ __forceinline__ f32x4 mfma16(bf16x8 a, bf16x8 b, f32x4 c) {
    return __builtin_amdgcn_mfma_f32_16x16x32_bf16(a, b, c, 0, 0, 0);
}
__device__ __forceinline__ f32x16 mfma32(bf16x8 a, bf16x8 b, f32x16 c) {
    return __builtin_amdgcn_mfma_f32_32x32x16_bf16(a, b, c, 0, 0, 0);
}
__device__ __forceinline__ u32 packbf(float lo, float hi) {
    union { __bf16 e[2]; u32 w; } u;
    u.e[0] = (__bf16)lo; u.e[1] = (__bf16)hi;
    return u.w;
}
__device__ __forceinline__ f32x16 zero16() {
    f32x16 z;
    #pragma unroll
    for (int i = 0; i < 16; i++) z[i] = 0.f;
    return z;
}

// ---------------- W fp32 -> bf16 (ws), vectorized ----------------
__global__ __launch_bounds__(256) void convert_w_kernel(
    const float* __restrict__ Wq, const float* __restrict__ Wk,
    const float* __restrict__ Wv, __bf16* __restrict__ wb)
{
    int i = blockIdx.x * 256 + threadIdx.x;      // 49152 threads, 4 elems each
    int m = i >> 14, off = (i & 16383) << 2;
    const float* s = (m == 0 ? Wq : (m == 1 ? Wk : Wv)) + off;
    float4 f = *(const float4*)s;
    bf16x4 h = { (__bf16)f.x, (__bf16)f.y, (__bf16)f.z, (__bf16)f.w };
    *(bf16x4*)(wb + (m << 16) + off) = h;
}

// ------ QKV projection (M=16384,N=192,K=1024) + fused RoPE + q-prescale ------
// Double-buffered reg-staged pipeline: one barrier per K-iteration.
__global__ __launch_bounds__(256) void proj_kernel(
    const float* __restrict__ x, const __bf16* __restrict__ wb,
    __bf16* __restrict__ qb, __bf16* __restrict__ kb, __bf16* __restrict__ vt)
{
    __shared__ __bf16 xs[2][32][72];
    __shared__ __bf16 wl[2][192][72];
    const int tid  = threadIdx.x;
    const int wave = tid >> 6, lane = tid & 63;
    const int l15 = lane & 15, l4 = lane >> 4;
    const size_t m0 = (size_t)blockIdx.x * 32;
    const int xrow = tid >> 3, xcp = (tid & 7) * 8;   // x stage: row, col*8
    const int wrow = tid >> 3, wcp = (tid & 7) * 8;   // W stage: +32 rows per j

    f32x4 acc[2][3];
    #pragma unroll
    for (int a = 0; a < 2; a++)
        #pragma unroll
        for (int bn = 0; bn < 3; bn++) acc[a][bn] = (f32x4){0.f, 0.f, 0.f, 0.f};

    const float* xsrc = x + (m0 + xrow) * 1024 + xcp;

    float4 rx0, rx1;
    bf16x8 rw[6];

    // prologue: tile 0 -> regs -> LDS buf 0
    rx0 = *(const float4*)(xsrc);
    rx1 = *(const float4*)(xsrc + 4);
    #pragma unroll
    for (int j = 0; j < 6; j++)
        rw[j] = *(const bf16x8*)(wb + (size_t)(wrow + j * 32) * 1024 + wcp);
    {
        bf16x8 h = {(__bf16)rx0.x, (__bf16)rx0.y, (__bf16)rx0.z, (__bf16)rx0.w,
                    (__bf16)rx1.x, (__bf16)rx1.y, (__bf16)rx1.z, (__bf16)rx1.w};
        *(bf16x8*)&xs[0][xrow][xcp] = h;
        #pragma unroll
        for (int j = 0; j < 6; j++)
            *(bf16x8*)&wl[0][wrow + j * 32][wcp] = rw[j];
    }
    __syncthreads();

    for (int t = 0; t < 16; t++) {
        const int cur = t & 1;
        if (t < 15) {   // issue next tile's loads early (overlap with compute)
            const int k0 = (t + 1) * 64;
            rx0 = *(const float4*)(xsrc + k0);
            rx1 = *(const float4*)(xsrc + k0 + 4);
            #pragma unroll
            for (int j = 0; j < 6; j++)
                rw[j] = *(const bf16x8*)(wb + (size_t)(wrow + j * 32) * 1024 + k0 + wcp);
        }
        // compute tile t from LDS[cur]
        bf16x8 af[2][2], bfr[3][2];
        #pragma unroll
        for (int mf = 0; mf < 2; mf++)
            #pragma unroll
            for (int c = 0; c < 2; c++)
                af[mf][c] = *(const bf16x8*)&xs[cur][mf * 16 + l15][c * 32 + l4 * 8];
        #pragma unroll
        for (int nf = 0; nf < 3; nf++)
            #pragma unroll
            for (int c = 0; c < 2; c++)
                bfr[nf][c] = *(const bf16x8*)&wl[cur][wave * 48 + nf * 16 + l15][c * 32 + l4 * 8];
        #pragma unroll
        for (int mf = 0; mf < 2; mf++)
            #pragma unroll
            for (int nf = 0; nf < 3; nf++)
                #pragma unroll
                for (int c = 0; c < 2; c++)
                    acc[mf][nf] = mfma16(af[mf][c], bfr[nf][c], acc[mf][nf]);
        if (t < 15) {   // stage tile t+1 into the other buffer
            bf16x8 h = {(__bf16)rx0.x, (__bf16)rx0.y, (__bf16)rx0.z, (__bf16)rx0.w,
                        (__bf16)rx1.x, (__bf16)rx1.y, (__bf16)rx1.z, (__bf16)rx1.w};
            *(bf16x8*)&xs[cur ^ 1][xrow][xcp] = h;
            #pragma unroll
            for (int j = 0; j < 6; j++)
                *(bf16x8*)&wl[cur ^ 1][wrow + j * 32][wcp] = rw[j];
        }
        __syncthreads();
    }

    // epilogue: C layout col = l15 (n), row = l4*4 + r (m); rope fused for q,k;
    // q additionally pre-scaled by (1/8)*log2(e) so flash softmax is base-2 direct.
    #pragma unroll
    for (int mf = 0; mf < 2; mf++) {
        #pragma unroll
        for (int nf = 0; nf < 3; nf++) {
            int n = wave * 48 + nf * 16 + l15;
            #pragma unroll
            for (int r = 0; r < 4; r++) {
                size_t mrow = m0 + mf * 16 + l4 * 4 + r;
                float val = acc[mf][nf][r];
                float partner = __shfl_xor(val, 1);
                if (n < 128) {
                    int i = (n & 63) >> 1;
                    int t = (int)(mrow & 4095);
                    float inv = __builtin_exp2f((float)i * (-13.287712379549449f / 32.f));
                    float ang = (float)t * inv;
                    float sn, cs;
                    __sincosf(ang, &sn, &cs);
                    float res = (n & 1) ? (partner * sn + val * cs)
                                        : (val * cs - partner * sn);
                    if (n < 64) {
                        res *= 0.180336884f;    // (1/8)*log2(e) folded into q
                        qb[mrow * 64 + n] = (__bf16)res;
                    } else {
                        kb[mrow * 64 + (n - 64)] = (__bf16)res;
                    }
                } else {
                    int bb = (int)(mrow >> 12), tt = (int)(mrow & 4095);
                    vt[((size_t)bb * 64 + (n - 128)) * 4096 + tt] = (__bf16)val;
                }
            }
        }
    }
}

// ---------------- causal flash attention, 32x32 MFMA, pi-permuted kv ----------
// 256 blocks = 4 batches x 64 pairs (jA=127-p heavy, jB=p light; 32-row q-blocks)
// 8 waves = 8 k-splits; wave owns all 32 q-rows. Swapped QK^T: lane -> one q col.
// K rows fed permuted (prow) so C slot i holds kv pi(i) and P->B-frag repack is
// a pure register rename (no cross-lane ops).
__global__ __launch_bounds__(512, 2) void flash_kernel(
    const __bf16* __restrict__ qb, const __bf16* __restrict__ kb,
    const __bf16* __restrict__ vt, float* __restrict__ out)
{
    __shared__ float ods[8][32][68];
    __shared__ float mls[2][8][32];

    const int tid = threadIdx.x;
    const int wave = tid >> 6, lane = tid & 63;
    const int l31 = lane & 31, h = lane >> 5;
    const int b = blockIdx.x & 3;
    const int p = blockIdx.x >> 2;
    // pi bit-shuffle: [b4 b3 b2 b1 b0] -> row with b3->16s, b2->8s, b4->4s
    const int prow = ((l31 >> 3) & 1) * 16 + ((l31 >> 2) & 1) * 8
                   + (l31 >> 4) * 4 + (l31 & 3);

    const __bf16* kbb = kb + (size_t)b * T_LEN * 64;
    const __bf16* vtb = vt + (size_t)b * 64 * T_LEN;

    #pragma unroll 1
    for (int half = 0; half < 2; half++) {
        const int jt = half ? p : 127 - p;
        const int q0 = jt * 32;
        const int qg = q0 + l31;

        // Q B-frags: col q = l31, k(d) = dc*16 + 8h + j  (q pre-scaled in proj)
        const __bf16* qp = qb + ((size_t)b * T_LEN + q0 + l31) * 64 + h * 8;
        bf16x8 qf[4];
        #pragma unroll
        for (int dc = 0; dc < 4; dc++) qf[dc] = *(const bf16x8*)(qp + dc * 16);

        float m = -1e30f, l = 0.f;
        f32x16 o0 = zero16(), o1 = zero16();
        const int nt = (jt >> 1) + 1;

        for (int kt = wave; kt < nt; kt += 8) {
            const int kc0 = kt << 6;
            // K A-frags, rows permuted by pi
            const __bf16* kr0 = kbb + (size_t)(kc0 + prow) * 64 + h * 8;
            const __bf16* kr1 = kr0 + 32 * 64;
            f32x16 s0 = zero16(), s1 = zero16();
            #pragma unroll
            for (int dc = 0; dc < 4; dc++) {
                s0 = mfma32(*(const bf16x8*)(kr0 + dc * 16), qf[dc], s0);
                s1 = mfma32(*(const bf16x8*)(kr1 + dc * 16), qf[dc], s1);
            }
            // V A-frags issued early: rows d = l31(+32), k-slot = cg*16 + 8h + j
            const __bf16* vr0 = vtb + (size_t)l31 * T_LEN + kc0 + h * 8;
            const __bf16* vr1 = vr0 + (size_t)32 * T_LEN;
            bf16x8 vf0[4], vf1[4];
            #pragma unroll
            for (int cg = 0; cg < 4; cg++) {
                vf0[cg] = *(const bf16x8*)(vr0 + cg * 16);
                vf1[cg] = *(const bf16x8*)(vr1 + cg * 16);
            }
            // causal mask only on diagonal-straddling tiles (wave-uniform guard)
            if (kc0 + 63 > q0) {
                #pragma unroll
                for (int r = 0; r < 16; r++) {
                    int koff = kc0 + ((r >> 2) & 1) * 16 + 8 * h
                             + (r >> 3) * 4 + (r & 3);
                    if (koff > qg)      s0[r] = -1e30f;
                    if (koff + 32 > qg) s1[r] = -1e30f;
                }
            }
            float tmax = -1e30f;
            #pragma unroll
            for (int r = 0; r < 16; r++) tmax = fmaxf(tmax, fmaxf(s0[r], s1[r]));
            tmax = fmaxf(tmax, __shfl_xor(tmax, 32));
            // defer-rescale (T13): skip o-rescale while max grows < 8 (log2 units)
            if (!__all(tmax <= m + 8.f)) {
                const float mnew = fmaxf(m, tmax);
                const float alpha = __builtin_exp2f(m - mnew);
                m = mnew;
                l *= alpha;
                #pragma unroll
                for (int r = 0; r < 16; r++) { o0[r] *= alpha; o1[r] *= alpha; }
            }
            float tsum = 0.f;
            #pragma unroll
            for (int r = 0; r < 16; r++) {
                float e0 = __builtin_exp2f(s0[r] - m);
                float e1 = __builtin_exp2f(s1[r] - m);
                s0[r] = e0; s1[r] = e1;
                tsum += e0 + e1;
            }
            tsum += __shfl_xor(tsum, 32);
            l += tsum;
            // P -> B-frags: pure register rename under pi (no shuffles)
            union { u32 w[4]; bf16x8 v; } pf[4];
            #pragma unroll
            for (int cg = 0; cg < 2; cg++) {
                pf[cg].w[0]     = packbf(s0[4 * cg + 0],  s0[4 * cg + 1]);
                pf[cg].w[1]     = packbf(s0[4 * cg + 2],  s0[4 * cg + 3]);
                pf[cg].w[2]     = packbf(s0[4 * cg + 8],  s0[4 * cg + 9]);
                pf[cg].w[3]     = packbf(s0[4 * cg + 10], s0[4 * cg + 11]);
                pf[cg + 2].w[0] = packbf(s1[4 * cg + 0],  s1[4 * cg + 1]);
                pf[cg + 2].w[1] = packbf(s1[4 * cg + 2],  s1[4 * cg + 3]);
                pf[cg + 2].w[2] = packbf(s1[4 * cg + 8],  s1[4 * cg + 9]);
                pf[cg + 2].w[3] = packbf(s1[4 * cg + 10], s1[4 * cg + 11]);
            }
            // PV: O^T += V^T P^T
            #pragma unroll
            for (int cg = 0; cg < 4; cg++) {
                o0 = mfma32(vf0[cg], pf[cg].v, o0);
                o1 = mfma32(vf1[cg], pf[cg].v, o1);
            }
        }

        // publish partials: O^T C-layout col q=l31, row d=(r&3)+8*(r>>2)+4h
        #pragma unroll
        for (int c2 = 0; c2 < 4; c2++) {
            f32x4 w0 = {o0[4 * c2], o0[4 * c2 + 1], o0[4 * c2 + 2], o0[4 * c2 + 3]};
            f32x4 w1 = {o1[4 * c2], o1[4 * c2 + 1], o1[4 * c2 + 2], o1[4 * c2 + 3]};
            *(f32x4*)&ods[wave][l31][8 * c2 + 4 * h]      = w0;
            *(f32x4*)&ods[wave][l31][32 + 8 * c2 + 4 * h] = w1;
        }
        if (h == 0) { mls[0][wave][l31] = m; mls[1][wave][l31] = l; }
        __syncthreads();

        // merge 8 splits: thread -> (q = tid>>4, dchunk = tid&15)
        {
            const int q = tid >> 4, dc = tid & 15;
            float M = -1e30f;
            #pragma unroll
            for (int s2 = 0; s2 < 8; s2++) M = fmaxf(M, mls[0][s2][q]);
            float w8[8], L = 0.f;
            #pragma unroll
            for (int s2 = 0; s2 < 8; s2++) {
                float ws = __builtin_exp2f(mls[0][s2][q] - M);
                w8[s2] = ws;
                L += ws * mls[1][s2][q];
            }
            const float invL = 1.f / L;
            f32x4 acc = {0.f, 0.f, 0.f, 0.f};
            #pragma unroll
            for (int s2 = 0; s2 < 8; s2++) {
                f32x4 part = *(const f32x4*)&ods[s2][q][dc * 4];
                acc.x += part.x * w8[s2];
                acc.y += part.y * w8[s2];
                acc.z += part.z * w8[s2];
                acc.w += part.w * w8[s2];
            }
            acc.x *= invL; acc.y *= invL; acc.z *= invL; acc.w *= invL;
            *(f32x4*)(out + ((size_t)b * T_LEN + q0 + q) * 64 + dc * 4) = acc;
        }
        __syncthreads();
    }
}

extern "C" void kernel_launch(void* const* d_in, const int* in_sizes, int n_in,
                              void* d_out, int out_size, void* d_ws, size_t ws_size,
                              hipStream_t stream)
{
    const float* x  = (const float*)d_in[0];
    const float* Wq = (const float*)d_in[1];
    const float* Wk = (const float*)d_in[2];
    const float* Wv = (const float*)d_in[3];
    float* out = (float*)d_out;

    __bf16* qb = (__bf16*)d_ws;          // 2 MB (rope applied, pre-scaled)
    __bf16* kb = qb + 1048576;           // 2 MB (rope applied)
    __bf16* vt = kb + 1048576;           // 2 MB (V transposed [b][d][t])
    __bf16* wb = vt + 1048576;           // 384 KB

    convert_w_kernel<<<192, 256, 0, stream>>>(Wq, Wk, Wv, wb);
    proj_kernel<<<512, 256, 0, stream>>>(x, wb, qb, kb, vt);
    flash_kernel<<<256, 512, 0, stream>>>(qb, kb, vt, out);
}